// Round 11
// baseline (350.759 us; speedup 1.0000x reference)
//
#include <hip/hip_runtime.h>
#include <stdint.h>

#define T_LEN 1024
#define NSTATE 32
#define RING 32

typedef int v2i __attribute__((ext_vector_type(2)));

__device__ __forceinline__ float max3f(float a, float b, float c) {
    return fmaxf(fmaxf(a, b), c);   // v_max3_f32
}
__device__ __forceinline__ int min3i(int a, int b, int c) {
    return min(min(a, b), c);       // v_min3_i32
}

// Two waves per block: wave 0 = MAIN (serial value chain), wave 1 = HELPER
// (deferred argmax + backpointer writes), synced lock-free via an LDS ring.
__launch_bounds__(128)
__global__ void viterbi_kernel(const float* __restrict__ logits,
                               const float* __restrict__ trans,
                               const int* __restrict__ seqlen,
                               int* __restrict__ out)
{
    const int tid  = threadIdx.x;   // 0..127
    const int wid  = tid >> 6;      // 0 = main, 1 = helper
    const int lane = tid & 63;
    const int half = lane >> 5;     // candidate half this lane reduces
    const int j    = lane & 31;     // output column (lanes j, j+32 duplicate)
    const int h16  = half * 16;

    __shared__ uint8_t bp[T_LEN * NSTATE];            // 32KB backptrs
    __shared__ __align__(16) char ovl[RING * NSTATE * 4];  // st_ring / pred overlay
    __shared__ uint8_t Farr[NSTATE * NSTATE];
    __shared__ uint8_t earr[NSTATE];
    __shared__ volatile int flag[RING];               // slot -> step stored
    __shared__ volatile int hp;                       // helper progress

    float (*st_ring)[NSTATE] = (float (*)[NSTATE])ovl;
    int* pred = (int*)ovl;                            // used only in epilogue

    if (tid < RING) flag[tid] = -1;
    if (tid == 0) hp = 0;

    int L = seqlen[blockIdx.x];
    L = min(max(L, 0), T_LEN);

    // transition column j, rows h16..h16+15 (both waves load identically)
    float tr[16];
#pragma unroll
    for (int k = 0; k < 16; ++k)
        tr[k] = trans[(h16 + k) * NSTATE + j];

    const float* lg = logits + (size_t)blockIdx.x * T_LEN * NSTATE;

    float ns = lg[j];    // running column value (meaningful on wave 0)

    __syncthreads();     // flags/hp initialized before any ring traffic

    int ft = 0;          // last tag (computed on wave 0)

    if (wid == 0) {
        // ================= MAIN: serial value chain =================
        st_ring[0][j] = ns;                       // publish S_0
        __asm__ __volatile__("" ::: "memory");
        flag[0] = 0;

        float4 q0, q1, q2, q3;
        {
            const float4* sv = (const float4*)(st_ring[0]) + half * 4;
            q0 = sv[0]; q1 = sv[1]; q2 = sv[2]; q3 = sv[3];
        }

        auto mstep = [&](int t, float lgt) {
            // hm = max over this half's 16 candidates (exact)
            float a0 = max3f(q0.x + tr[0],  q0.y + tr[1],  q0.z + tr[2]);
            float a1 = max3f(q0.w + tr[3],  q1.x + tr[4],  q1.y + tr[5]);
            float a2 = max3f(q1.z + tr[6],  q1.w + tr[7],  q2.x + tr[8]);
            float a3 = max3f(q2.y + tr[9],  q2.z + tr[10], q2.w + tr[11]);
            float a4 = max3f(q3.x + tr[12], q3.y + tr[13], q3.z + tr[14]);
            float b0 = max3f(a0, a1, a2);
            float b1 = max3f(a3, a4, q3.w + tr[15]);
            float hm = fmaxf(b0, b1);

            v2i sw = __builtin_amdgcn_permlane32_swap(__float_as_int(hm),
                                                      __float_as_int(hm), false, false);
            float gm = fmaxf(hm, fmaxf(__int_as_float(sw[0]), __int_as_float(sw[1])));

            ns = gm + lgt;               // same single-rounding add order as ref

            // ring throttle: helper must have consumed the slot we recycle.
            // guarantees helper_progress >= t-24 (need >= t-31).
            if ((t & 7) == 0) { while (t - hp > 16) {} }

            int slot = t & (RING - 1);
            st_ring[slot][j] = ns;                    // publish S_t
            __asm__ __volatile__("" ::: "memory");
            flag[slot] = t;                           // then the flag (pipe FIFO)

            const float4* sv = (const float4*)(st_ring[slot]) + half * 4;
            q0 = sv[0]; q1 = sv[1]; q2 = sv[2]; q3 = sv[3];   // own roundtrip
        };

        if (L >= 2) {
            float pre[8];
#pragma unroll
            for (int d = 0; d < 8; ++d)
                pre[d] = lg[min(1 + d, T_LEN - 1) * NSTATE + j];
            int t = 1;
            for (; t + 8 <= L; t += 8) {
#pragma unroll
                for (int u = 0; u < 8; ++u) {
                    mstep(t + u, pre[u]);
                    pre[u] = lg[min(t + 8 + u, T_LEN - 1) * NSTATE + j];
                }
            }
            for (int k2 = 0; t < L; ++t, ++k2) mstep(t, pre[k2]);
        }

        // last_tag = argmax(final state); lanes j and j+32 hold same value
        float m2 = ns;
#pragma unroll
        for (int d = 1; d < 64; d <<= 1) m2 = fmaxf(m2, __shfl_xor(m2, d));
        int ii = (ns == m2) ? j : 64;
#pragma unroll
        for (int d = 1; d < 64; d <<= 1) ii = min(ii, __shfl_xor(ii, d));
        ft = ii;
    } else {
        // ================= HELPER: deferred argmax + bp =================
        if (L >= 2) {
            for (int t = 1; t < L; ++t) {
                const int tS = t - 1;
                const int slot = tS & (RING - 1);
                while (flag[slot] < tS) {}            // uniform spin
                __asm__ __volatile__("" ::: "memory");

                const float4* sv = (const float4*)(st_ring[slot]) + half * 4;
                float4 q0 = sv[0], q1 = sv[1], q2 = sv[2], q3 = sv[3];

                float v[16];
                v[0]=q0.x+tr[0];  v[1]=q0.y+tr[1];  v[2]=q0.z+tr[2];  v[3]=q0.w+tr[3];
                v[4]=q1.x+tr[4];  v[5]=q1.y+tr[5];  v[6]=q1.z+tr[6];  v[7]=q1.w+tr[7];
                v[8]=q2.x+tr[8];  v[9]=q2.y+tr[9];  v[10]=q2.z+tr[10];v[11]=q2.w+tr[11];
                v[12]=q3.x+tr[12];v[13]=q3.y+tr[13];v[14]=q3.z+tr[14];v[15]=q3.w+tr[15];

                // recompute gm (bit-exact: max is order-independent)
                float a0 = max3f(v[0],  v[1],  v[2]);
                float a1 = max3f(v[3],  v[4],  v[5]);
                float a2 = max3f(v[6],  v[7],  v[8]);
                float a3 = max3f(v[9],  v[10], v[11]);
                float a4 = max3f(v[12], v[13], v[14]);
                float b0 = max3f(a0, a1, a2);
                float b1 = max3f(a3, a4, v[15]);
                float hm = fmaxf(b0, b1);
                v2i sw = __builtin_amdgcn_permlane32_swap(__float_as_int(hm),
                                                          __float_as_int(hm), false, false);
                float gm = fmaxf(hm, fmaxf(__int_as_float(sw[0]), __int_as_float(sw[1])));

                // exact first-occurrence argmax
                int ix[16];
#pragma unroll
                for (int k = 0; k < 16; ++k)
                    ix[k] = (v[k] == gm) ? (h16 + k) : 64;
                int c0 = min3i(ix[0],  ix[1],  ix[2]);
                int c1 = min3i(ix[3],  ix[4],  ix[5]);
                int c2 = min3i(ix[6],  ix[7],  ix[8]);
                int c3 = min3i(ix[9],  ix[10], ix[11]);
                int c4 = min3i(ix[12], ix[13], ix[14]);
                int d0 = min3i(c0, c1, c2);
                int d1 = min3i(c3, c4, ix[15]);
                int ih = min(d0, d1);
                v2i swi = __builtin_amdgcn_permlane32_swap(ih, ih, false, false);
                int idx = min3i(ih, swi[0], swi[1]);

                bp[t * NSTATE + j] = (uint8_t)idx;    // dup same-value write

                if ((t & 15) == 0) hp = t;            // progress (benign dup)
            }
            hp = T_LEN;                               // release main fully
        }
    }

    __syncthreads();   // bp complete & visible; st_ring dead from here

    // ---- phase 1: chunk functions, all 32 start states (wave 0) ----
    if (wid == 0) {
        const int c = lane & 31;
        const int j0base = (lane >> 5) * 16;
        int tags[16];
#pragma unroll
        for (int k = 0; k < 16; ++k) tags[k] = j0base + k;
        const int thi = c * 32 + 31;
        for (int s = 0; s < 32; ++s) {
            int t = thi - s;
            bool valid = (t >= 1) && (t <= L - 1);
            int tc = min(max(t, 1), max(L - 1, 1));
            int base = tc * NSTATE;
#pragma unroll
            for (int k = 0; k < 16; ++k) {
                int nt = bp[base + tags[k]];
                tags[k] = valid ? nt : tags[k];
            }
        }
#pragma unroll
        for (int k = 0; k < 16; ++k)
            Farr[c * 32 + j0base + k] = (uint8_t)tags[k];
    }
    __syncthreads();

    // ---- phase 2: compose chunk entries (serial, 32 steps) ----
    if (tid == 0) {
        int e = ft;
        for (int c2 = 31; c2 >= 0; --c2) {
            earr[c2] = (uint8_t)e;
            e = Farr[c2 * 32 + e];
        }
    }
    __syncthreads();

    // ---- phase 3: re-walk chunks in parallel, emit pred (predication
    //      handles L<2: pred[t]=0 for t>=L, pred[0]=ft when L==1) ----
    if (wid == 0 && lane < 32) {
        int tag = earr[lane];
        const int thi3 = lane * 32 + 31;
        for (int s = 0; s < 32; ++s) {
            int t = thi3 - s;
            pred[t] = (t < L) ? tag : 0;
            bool valid = (t >= 1) && (t <= L - 1);
            int tc = min(max(t, 1), max(L - 1, 1));
            int nt = bp[tc * NSTATE + tag];
            tag = valid ? nt : tag;
        }
    }
    __syncthreads();

    // ---------------- coalesced store (wave 0) ----------------
    if (wid == 0) {
        int4* out4 = reinterpret_cast<int4*>(out + (size_t)blockIdx.x * T_LEN);
        const int4* p4 = reinterpret_cast<const int4*>(pred);
#pragma unroll
        for (int r = 0; r < 4; ++r)
            out4[r * 64 + lane] = p4[r * 64 + lane];
    }
}

extern "C" void kernel_launch(void* const* d_in, const int* in_sizes, int n_in,
                              void* d_out, int out_size, void* d_ws, size_t ws_size,
                              hipStream_t stream) {
    const float* logits = (const float*)d_in[0];
    const float* trans  = (const float*)d_in[1];
    const int*   slen   = (const int*)d_in[2];
    int*         out    = (int*)d_out;
    const int B = in_sizes[2];   // 1024

    viterbi_kernel<<<dim3(B), dim3(128), 0, stream>>>(logits, trans, slen, out);
}